// Round 1
// baseline (146.150 us; speedup 1.0000x reference)
//
#include <hip/hip_runtime.h>

// Symmetrizer for MAX_L=3: out[:,:,0,:] = in[:,:,0,:];
// out[:,:,1+s,:] = sum_{k: slots[k]==s} pref[k] * in[:,:,idx[k,0],:] * in[:,:,idx[k,1],:]
//
// Shapes (from reference): in (N, R, 20, 16) f32, out (N, R, 4, 16) f32.
// Memory-bound: 512 MB read + 102 MB write -> ~98 us floor @ 6.3 TB/s.

constexpr int N_ANG   = 20;  // angular basis size for MAX_L=3
constexpr int N_PAIRS = 19;  // 3 + 6 + 10
constexpr int OUT_ANG = 4;   // 1 + MAX_L slots

__global__ __launch_bounds__(256) void symmetrizer_kernel(
    const float4* __restrict__ in,     // [rows][N_ANG][4] (float4 over 16 channels)
    const float*  __restrict__ pref,   // [N_PAIRS]
    const int*    __restrict__ idx,    // [N_PAIRS][2]
    const int*    __restrict__ slots,  // [N_PAIRS]
    float4*       __restrict__ out,    // [rows][OUT_ANG][4]
    int nthreads)
{
    int tid = blockIdx.x * blockDim.x + threadIdx.x;
    if (tid >= nthreads) return;

    int row = tid >> 2;   // (node, radial) flat row
    int c4  = tid & 3;    // which float4 of the 16 channels

    const float4* ib = in + (size_t)row * (N_ANG * 4) + c4;

    // slot accumulators (named scalars of float4 -> stay in VGPRs)
    float4 s0 = make_float4(0.f, 0.f, 0.f, 0.f);
    float4 s1 = make_float4(0.f, 0.f, 0.f, 0.f);
    float4 s2 = make_float4(0.f, 0.f, 0.f, 0.f);

    // angular 0 passthrough
    float4 o0 = ib[0];

#pragma unroll
    for (int k = 0; k < N_PAIRS; ++k) {
        // table reads: compile-time k -> wave-uniform scalar loads
        int   a0 = idx[2 * k];
        int   a1 = idx[2 * k + 1];
        float p  = pref[k];
        int   sl = slots[k];

        float4 va = ib[a0 * 4];
        float4 vb = ib[a1 * 4];   // same address in practice -> L1 hit

        float4 w;
        w.x = p * va.x * vb.x;
        w.y = p * va.y * vb.y;
        w.z = p * va.z * vb.z;
        w.w = p * va.w * vb.w;

        // sl is wave-uniform -> uniform branch, no divergence
        if (sl == 0) {
            s0.x += w.x; s0.y += w.y; s0.z += w.z; s0.w += w.w;
        } else if (sl == 1) {
            s1.x += w.x; s1.y += w.y; s1.z += w.z; s1.w += w.w;
        } else {
            s2.x += w.x; s2.y += w.y; s2.z += w.z; s2.w += w.w;
        }
    }

    float4* ob = out + (size_t)row * (OUT_ANG * 4) + c4;
    ob[0]  = o0;
    ob[4]  = s0;
    ob[8]  = s1;
    ob[12] = s2;
}

extern "C" void kernel_launch(void* const* d_in, const int* in_sizes, int n_in,
                              void* d_out, int out_size, void* d_ws, size_t ws_size,
                              hipStream_t stream) {
    const float* node_attr = (const float*)d_in[0];
    const float* pref      = (const float*)d_in[1];
    const int*   idx       = (const int*)d_in[2];
    const int*   slots     = (const int*)d_in[3];
    float*       out       = (float*)d_out;

    // rows = N_NODES * N_RADIAL; each input row is N_ANG*16 floats
    int rows = in_sizes[0] / (N_ANG * 16);
    int nthreads = rows * 4;  // one thread per (row, channel-quad)

    int block = 256;
    int grid  = (nthreads + block - 1) / block;

    symmetrizer_kernel<<<grid, block, 0, stream>>>(
        (const float4*)node_attr, pref, idx, slots, (float4*)out, nthreads);
}

// Round 3
// 116.087 us; speedup vs baseline: 1.2590x; 1.2590x over previous
//
#include <hip/hip_runtime.h>

// Symmetrizer for MAX_L=3.
//   out[:,:,0,:]   = in[:,:,0,:]
//   out[:,:,1+s,:] = sum_{k: slot[k]==s} pref[k] * in[:,:,k+1,:]^2
//
// Tables from _build_tables(MAX_L=3), recomputed by hand (round-1 had a
// transcription bug in the l=3 tail):
//   indices[k] = (k+1, k+1)  (every pair is a square)
//   l=1 (ang 1..3,  slot 0): pref 1,1,1
//   l=2 (ang 4..9,  slot 1): pref 1,2,2,1,2,1
//   l=3 (ang 10..19,slot 2): pref 1,3,3,3,6,3,1,3,3,1
//     order: (3,0,0),(2,1,0),(2,0,1),(1,2,0),(1,1,1),(1,0,2),
//            (0,3,0),(0,2,1),(0,1,2),(0,0,3)
//
// Shapes: in (N*R, 20, 16) f32, out (N*R, 4, 16) f32. Memory-bound:
// 512 MB read + 102 MB write -> ~98 us floor @ 6.3 TB/s achievable.

constexpr int N_ANG   = 20;
constexpr int OUT_ANG = 4;

__global__ __launch_bounds__(256) void symmetrizer_kernel(
    const float4* __restrict__ in,   // [rows][N_ANG][4]
    float4*       __restrict__ out,  // [rows][OUT_ANG][4]
    int nthreads)
{
    int tid = blockIdx.x * blockDim.x + threadIdx.x;
    if (tid >= nthreads) return;

    int row = tid >> 2;   // (node, radial) flat row
    int c4  = tid & 3;    // which float4 of the 16 channels

    const float4* ib = in + (size_t)row * (N_ANG * 4) + c4;

    // 20 independent coalesced loads (compile-time offsets -> max MLP)
    float4 v0  = ib[0 * 4],  v1  = ib[1 * 4],  v2  = ib[2 * 4],  v3  = ib[3 * 4];
    float4 v4  = ib[4 * 4],  v5  = ib[5 * 4],  v6  = ib[6 * 4],  v7  = ib[7 * 4];
    float4 v8  = ib[8 * 4],  v9  = ib[9 * 4],  v10 = ib[10 * 4], v11 = ib[11 * 4];
    float4 v12 = ib[12 * 4], v13 = ib[13 * 4], v14 = ib[14 * 4], v15 = ib[15 * 4];
    float4 v16 = ib[16 * 4], v17 = ib[17 * 4], v18 = ib[18 * 4], v19 = ib[19 * 4];

#define SQ_ACC(acc, v, p)                    \
    do {                                     \
        acc.x += (p) * (v).x * (v).x;        \
        acc.y += (p) * (v).y * (v).y;        \
        acc.z += (p) * (v).z * (v).z;        \
        acc.w += (p) * (v).w * (v).w;        \
    } while (0)

    // slot 0 (l=1): pref 1,1,1
    float4 s0 = make_float4(0.f, 0.f, 0.f, 0.f);
    SQ_ACC(s0, v1, 1.f); SQ_ACC(s0, v2, 1.f); SQ_ACC(s0, v3, 1.f);

    // slot 1 (l=2): pref 1,2,2,1,2,1
    float4 s1 = make_float4(0.f, 0.f, 0.f, 0.f);
    SQ_ACC(s1, v4, 1.f); SQ_ACC(s1, v5, 2.f); SQ_ACC(s1, v6, 2.f);
    SQ_ACC(s1, v7, 1.f); SQ_ACC(s1, v8, 2.f); SQ_ACC(s1, v9, 1.f);

    // slot 2 (l=3): pref 1,3,3,3,6,3,1,3,3,1
    float4 s2 = make_float4(0.f, 0.f, 0.f, 0.f);
    SQ_ACC(s2, v10, 1.f); SQ_ACC(s2, v11, 3.f); SQ_ACC(s2, v12, 3.f);
    SQ_ACC(s2, v13, 3.f); SQ_ACC(s2, v14, 6.f); SQ_ACC(s2, v15, 3.f);
    SQ_ACC(s2, v16, 1.f); SQ_ACC(s2, v17, 3.f); SQ_ACC(s2, v18, 3.f);
    SQ_ACC(s2, v19, 1.f);

#undef SQ_ACC

    float4* ob = out + (size_t)row * (OUT_ANG * 4) + c4;
    ob[0]  = v0;   // angular-0 passthrough
    ob[4]  = s0;
    ob[8]  = s1;
    ob[12] = s2;
}

extern "C" void kernel_launch(void* const* d_in, const int* in_sizes, int n_in,
                              void* d_out, int out_size, void* d_ws, size_t ws_size,
                              hipStream_t stream) {
    const float* node_attr = (const float*)d_in[0];
    float*       out       = (float*)d_out;

    int rows = in_sizes[0] / (N_ANG * 16);
    int nthreads = rows * 4;  // one thread per (row, channel-quad)

    int block = 256;
    int grid  = (nthreads + block - 1) / block;

    symmetrizer_kernel<<<grid, block, 0, stream>>>(
        (const float4*)node_attr, (float4*)out, nthreads);
}